// Round 7
// baseline (1381.886 us; speedup 1.0000x reference)
//
#include <hip/hip_runtime.h>
#include <stdint.h>

#define H 512
#define B_SZ 1024
#define T_WARM 256
#define NSTEPS 64
#define TLOOP (T_WARM + NSTEPS - 1)   // 319 steps: epilogue of t produces h_{t+1} and y_{t+1}

#define RPB 16          // rows per team
#define NTEAM 64        // B_SZ / RPB
#define NCG 4           // col groups (blocks per team)
#define NBLK 256        // NTEAM * NCG == CU count, 1 block/CU
#define NTHR 512        // 8 waves, each: 16 cols x K=512
#define ROWB 1024       // LDS h row stride bytes; swizzle byte ^= (row&7)<<4 on BOTH sides

typedef __attribute__((ext_vector_type(8))) short bf16x8;
typedef __attribute__((ext_vector_type(4))) float f32x4;

static __device__ __forceinline__ ushort f2bf(float f) {
    uint32_t u = __builtin_bit_cast(uint32_t, f);
    u += 0x7FFFu + ((u >> 16) & 1u);
    return (ushort)(u >> 16);
}
static __device__ __forceinline__ float bf2f(ushort h) {
    uint32_t u = ((uint32_t)h) << 16;
    return __builtin_bit_cast(float, u);
}

__global__ void prep_kernel(const float* __restrict__ x,
                            const float* __restrict__ W_hh,
                            const float* __restrict__ b_ih,
                            const float* __restrict__ b_hh,
                            ushort* __restrict__ Wh, ushort* __restrict__ Wl,
                            float* __restrict__ bias, float* __restrict__ xT,
                            uint32_t* __restrict__ HbH0, uint32_t* __restrict__ HbL0,
                            float* __restrict__ Yacc, uint32_t* __restrict__ flags) {
    int i = blockIdx.x * NTHR + threadIdx.x;     // 512 blocks x 512 = 262144
    HbH0[i] = 0u; HbL0[i] = 0u;                  // h(0)=0 planes (belt & braces)
    if (i < 4096) flags[i] = 0u;
    if (i < B_SZ * NSTEPS) Yacc[i] = 0.f;
    {   // i < H*H == 262144
        float w = W_hh[i];
        ushort hi = f2bf(w);
        Wh[i] = hi;
        Wl[i] = f2bf(w - bf2f(hi));
    }
    {   // i < B_SZ*T_WARM == 262144
        int b = i & (B_SZ - 1), t = i >> 10;
        xT[t * B_SZ + b] = x[b * T_WARM + t];
    }
    if (i < H) bias[i] = b_ih[i] + b_hh[i];
}

__global__ void fix_kernel(const float* __restrict__ Yacc,
                           const float* __restrict__ b_fc_p,
                           float* __restrict__ out) {
    int i = blockIdx.x * 256 + threadIdx.x;      // 65536 = B_SZ*NSTEPS
    out[i] = Yacc[i] + b_fc_p[0];
}

// R6 skeleton + (1) rollout rank-1 fold W' = W_hh + w_in (x) wfc, bias' = bias
// + bfc*w_in — rollout steps identical to warm steps, y recovered off critical
// path via epilogue partials + atomicAdd after flag publish; (2) (row&7)<<4
// swizzle; (3) hi/lo plane-split comm, producer pair-packs, consumer writes
// b64 direct — no repack VALU; loads issued before barrier A.
__global__ __launch_bounds__(NTHR, 1)
void rnn_kernel(const float* __restrict__ xT,
                const float* __restrict__ W_ih,
                const float* __restrict__ b_fc_p,
                const float* __restrict__ W_fc,
                const ushort* __restrict__ Wh_g,
                const ushort* __restrict__ Wl_g,
                const float* __restrict__ bias_g,
                uint32_t* __restrict__ HbH0, uint32_t* __restrict__ HbH1,
                uint32_t* __restrict__ HbL0, uint32_t* __restrict__ HbL1,
                float* __restrict__ Yacc,
                uint32_t* __restrict__ flags) {
    __shared__ __align__(16) ushort h_hi[2][RPB * 512];   // ping-pong hi, 16 KB each
    __shared__ __align__(16) ushort h_lo[2][RPB * 512];   // ping-pong lo
    __shared__ __align__(16) float  w_fc_s[H];

    const int tid  = threadIdx.x;
    const int bid  = blockIdx.x;
    const int team = bid & (NTEAM - 1);   // blocks {team,+64,+128,+192}: same XCD
    const int cg   = bid >> 6;            // 0..3
    const int row0 = team * RPB;
    const int col0 = cg * 128;

    const int lane = tid & 63;
    const int wv   = tid >> 6;            // 0..7: own 16-col tile; also staged 64-col slice
    const int n    = lane & 15, q = lane >> 4;
    const bool selfw = ((wv >> 1) == cg);

    w_fc_s[tid] = W_fc[tid];
    for (int i = tid; i < RPB * 512; i += NTHR) { h_hi[0][i] = 0; h_lo[0][i] = 0; }

    // ---- weights register-resident, ROTATED: slot i <-> global kt (cg*4+i)&15 ----
    bf16x8 Bh[16], Bl[16];
    {
        const ushort* wh = Wh_g + (col0 + wv * 16 + n) * H + q * 8;
        const ushort* wl = Wl_g + (col0 + wv * 16 + n) * H + q * 8;
        #pragma unroll
        for (int i = 0; i < 16; ++i) {
            const int ktg = (cg * 4 + i) & 15;
            Bh[i] = *(const bf16x8*)(wh + ktg * 32);
            Bl[i] = *(const bf16x8*)(wl + ktg * 32);
        }
    }
    const int jcol  = col0 + wv * 16 + n;
    const float wi  = W_ih[jcol];
    const float wfcj = W_fc[jcol];
    float bj = bias_g[jcol];
    const float bfc = b_fc_p[0];

    // flags: [team][cg][half][slot]; producer wave wv -> (cg, wv>>2, wv&3)
    uint32_t* const myflag =
        flags + (((team * NCG + cg) * 2 + (wv >> 2)) << 2) + (wv & 3);
    const uint64_t* const pollp =
        (const uint64_t*)(flags + (((team * NCG + (wv >> 1)) * 2 + (wv & 1)) << 2));

    char* const hb0c = (char*)&h_hi[0][0];
    char* const hb1c = (char*)&h_hi[1][0];
    char* const lb0c = (char*)&h_lo[0][0];
    char* const lb1c = (char*)&h_lo[1][0];

    __syncthreads();

    for (int t = 0; t < TLOOP; ++t) {
        const int pp = t & 1;
        const bool roll = (t >= T_WARM);

        // ---- one-time rank-1 fold at rollout entry (all indices static) ----
        if (t == T_WARM) {
            #pragma unroll
            for (int i = 0; i < 16; ++i) {
                const int ktg = (cg * 4 + i) & 15;
                const float* wf = &w_fc_s[ktg * 32 + q * 8];
                f32x4 w0 = *(const f32x4*)wf;
                f32x4 w1 = *(const f32x4*)(wf + 4);
                #pragma unroll
                for (int j = 0; j < 8; ++j) {
                    const float wk = (j < 4) ? w0[j] : w1[j - 4];
                    float v = bf2f((ushort)Bh[i][j]) + bf2f((ushort)Bl[i][j]) + wi * wk;
                    const ushort hb16 = f2bf(v);
                    Bh[i][j] = (short)hb16;
                    Bl[i][j] = (short)f2bf(v - bf2f(hb16));
                }
            }
            bj += bfc * wi;
        }

        f32x4 xq = {0.f, 0.f, 0.f, 0.f};
        if (!roll) xq = *(const f32x4*)(xT + t * B_SZ + row0 + q * 4);

        // ---- staging waves: poll + issue plane loads BEFORE barrier A ----
        uint64_t tmpH[4], tmpL[4];
        const bool stage = (!selfw) && (t > 0);
        if (stage) {
            const uint32_t need = (uint32_t)t;
            while (true) {
                uint64_t f = __hip_atomic_load(pollp, __ATOMIC_RELAXED, __HIP_MEMORY_SCOPE_AGENT);
                if ((uint32_t)f >= need && (uint32_t)(f >> 32) >= need) break;
                __builtin_amdgcn_s_sleep(1);
            }
            const uint64_t* sH = (const uint64_t*)(pp ? HbH1 : HbH0);
            const uint64_t* sL = (const uint64_t*)(pp ? HbL1 : HbL0);
            #pragma unroll
            for (int it = 0; it < 4; ++it) {
                int idx = it * 64 + lane;            // [0,256): r = idx>>4, u = idx&15
                int r = idx >> 4, u = idx & 15;
                size_t off = (size_t)(row0 + r) * 128 + wv * 16 + u;
                tmpH[it] = __hip_atomic_load(sH + off, __ATOMIC_RELAXED, __HIP_MEMORY_SCOPE_AGENT);
                tmpL[it] = __hip_atomic_load(sL + off, __ATOMIC_RELAXED, __HIP_MEMORY_SCOPE_AGENT);
            }
        }

        __syncthreads();   // A: epilogue(t-1) self LDS-writes visible

        // ---- phase 1: self-K MFMA — register slots 0..3 ----
        const char* ha = pp ? hb1c : hb0c;
        const char* la = pp ? lb1c : lb0c;
        const int aoffs = n * ROWB + q * 16;
        const int aswz  = (n & 7) << 4;
        f32x4 a0 = {0.f, 0.f, 0.f, 0.f}, a1 = {0.f, 0.f, 0.f, 0.f};
        #pragma unroll
        for (int kk = 0; kk < 4; ++kk) {
            const int ktg = cg * 4 + kk;             // runtime ADDRESS only
            const int b0 = (aoffs + ktg * 64) ^ aswz;
            bf16x8 ah = *(const bf16x8*)(ha + b0);
            bf16x8 al = *(const bf16x8*)(la + b0);
            f32x4& ac = (kk & 1) ? a1 : a0;
            ac = __builtin_amdgcn_mfma_f32_16x16x32_bf16(ah, Bh[kk], ac, 0, 0, 0);
            ac = __builtin_amdgcn_mfma_f32_16x16x32_bf16(al, Bh[kk], ac, 0, 0, 0);
            ac = __builtin_amdgcn_mfma_f32_16x16x32_bf16(ah, Bl[kk], ac, 0, 0, 0);
        }

        // ---- staging waves: b64 direct into LDS (no repack) ----
        if (stage) {
            char* hb = pp ? hb1c : hb0c;
            char* lb = pp ? lb1c : lb0c;
            #pragma unroll
            for (int it = 0; it < 4; ++it) {
                int idx = it * 64 + lane;
                int r = idx >> 4, u = idx & 15;
                int byte = (r * ROWB + wv * 128 + u * 8) ^ ((r & 7) << 4);
                *(uint64_t*)(hb + byte) = tmpH[it];
                *(uint64_t*)(lb + byte) = tmpL[it];
            }
        }
        __syncthreads();   // E: all remote slices staged

        // ---- phase 2: remote-K MFMA — register slots 4..15 ----
        #pragma unroll
        for (int i = 4; i < 16; ++i) {
            const int ktg = (cg * 4 + i) & 15;
            const int b0 = (aoffs + ktg * 64) ^ aswz;
            bf16x8 ah = *(const bf16x8*)(ha + b0);
            bf16x8 al = *(const bf16x8*)(la + b0);
            f32x4& ac = (i & 1) ? a1 : a0;
            ac = __builtin_amdgcn_mfma_f32_16x16x32_bf16(ah, Bh[i], ac, 0, 0, 0);
            ac = __builtin_amdgcn_mfma_f32_16x16x32_bf16(al, Bh[i], ac, 0, 0, 0);
            ac = __builtin_amdgcn_mfma_f32_16x16x32_bf16(ah, Bl[i], ac, 0, 0, 0);
        }

        // ---- epilogue: v = acc (+x*w_in) + bias', relu, split, publish ----
        uint32_t* dH = pp ? HbH0 : HbH1;     // next-state planes
        uint32_t* dL = pp ? HbL0 : HbL1;
        char* dh = pp ? hb0c : hb1c;         // next LDS buffer (self cols)
        char* dl = pp ? lb0c : lb1c;
        const int colp2 = (col0 + wv * 16 + (n & ~1)) * 2;     // LDS byte col base (pair)
        const size_t gcol = (size_t)((col0 + wv * 16) >> 1) + (n >> 1);
        const bool capy = (t >= T_WARM - 1);
        float sarr[4];
        #pragma unroll
        for (int i = 0; i < 4; ++i) {
            const int m = q * 4 + i;           // C/D: row = quad*4+reg, col = n
            float v = a0[i] + a1[i] + bj;
            if (!roll) v += xq[i] * wi;
            v = fmaxf(v, 0.f);
            sarr[i] = v * wfcj;
            const ushort hb16 = f2bf(v);
            const ushort lb16 = f2bf(v - bf2f(hb16));
            const uint32_t pk = ((uint32_t)hb16 << 16) | lb16;
            const uint32_t nb = __shfl_xor(pk, 1);
            uint32_t pw;                       // even lane: hi-pair word; odd: lo-pair word
            if ((n & 1) == 0) pw = (pk >> 16) | (nb & 0xFFFF0000u);
            else              pw = (nb & 0xFFFFu) | (pk << 16);
            uint32_t* gdst = ((n & 1) ? dL : dH) + (size_t)(row0 + m) * 256 + gcol;
            __hip_atomic_store(gdst, pw, __ATOMIC_RELAXED, __HIP_MEMORY_SCOPE_AGENT);
            const int sbyte = (m * ROWB + colp2) ^ ((m & 7) << 4);
            *(uint32_t*)(((n & 1) ? dl : dh) + sbyte) = pw;
        }

        // ---- y partial: reduce over this wave's 16 cols (off critical path) ----
        if (capy) {
            #pragma unroll
            for (int i = 0; i < 4; ++i) {
                float s = sarr[i];
                s += __shfl_xor(s, 1); s += __shfl_xor(s, 2);
                s += __shfl_xor(s, 4); s += __shfl_xor(s, 8);
                sarr[i] = s;
            }
        }

        asm volatile("s_waitcnt vmcnt(0)" ::: "memory");
        if (lane == 0)
            __hip_atomic_store(myflag, (uint32_t)(t + 1),
                               __ATOMIC_RELAXED, __HIP_MEMORY_SCOPE_AGENT);

        // atomics AFTER flag publish: never on the drain path
        if (capy && n == 0) {
            #pragma unroll
            for (int i = 0; i < 4; ++i)
                atomicAdd(Yacc + (size_t)(row0 + q * 4 + i) * NSTEPS + (t + 1 - T_WARM),
                          sarr[i]);
        }
    }
}

extern "C" void kernel_launch(void* const* d_in, const int* in_sizes, int n_in,
                              void* d_out, int out_size, void* d_ws, size_t ws_size,
                              hipStream_t stream) {
    const float* x    = (const float*)d_in[0];
    const float* W_ih = (const float*)d_in[1];
    const float* W_hh = (const float*)d_in[2];
    const float* b_ih = (const float*)d_in[3];
    const float* b_hh = (const float*)d_in[4];
    const float* W_fc = (const float*)d_in[5];
    const float* b_fc = (const float*)d_in[6];
    float* out = (float*)d_out;

    // ws carve (bytes): Wh 512K | Wl 512K | bias 4K | xT 1M | HbH0 1M | HbH1 1M |
    //                   HbL0 1M | HbL1 1M | Yacc 256K | flags 16K   (~6.6 MB)
    uint8_t* w = (uint8_t*)d_ws;
    ushort*   Wh    = (ushort*)(w);
    ushort*   Wl    = (ushort*)(w + 524288);
    float*    bias  = (float*)(w + 1048576);
    float*    xT    = (float*)(w + 1052672);
    uint32_t* HbH0  = (uint32_t*)(w + 2101248);
    uint32_t* HbH1  = (uint32_t*)(w + 3149824);
    uint32_t* HbL0  = (uint32_t*)(w + 4198400);
    uint32_t* HbL1  = (uint32_t*)(w + 5246976);
    float*    Yacc  = (float*)(w + 6295552);
    uint32_t* flags = (uint32_t*)(w + 6557696);

    prep_kernel<<<512, NTHR, 0, stream>>>(x, W_hh, b_ih, b_hh, Wh, Wl, bias, xT,
                                          HbH0, HbL0, Yacc, flags);
    rnn_kernel<<<NBLK, NTHR, 0, stream>>>(xT, W_ih, b_fc, W_fc, Wh, Wl, bias,
                                          HbH0, HbH1, HbL0, HbL1, Yacc, flags);
    fix_kernel<<<256, 256, 0, stream>>>(Yacc, b_fc, out);
}